// Round 1
// baseline (749.860 us; speedup 1.0000x reference)
//
#include <hip/hip_runtime.h>

typedef unsigned short u16;
typedef __attribute__((ext_vector_type(8))) short bf16x8;
typedef __attribute__((ext_vector_type(4))) float f32x4;

__device__ __forceinline__ u16 f2bf(float f) {
  union { float f; unsigned u; } v; v.f = f;
  unsigned r = v.u + 0x7FFFu + ((v.u >> 16) & 1u);
  return (u16)(r >> 16);
}

// transpose + convert: in [R][C] f32 -> out [Cout][R] bf16 (rows c>=C are zero)
__global__ __launch_bounds__(256)
void tr_cvt_k(const float* __restrict__ in, u16* __restrict__ out,
              int R, int C, int Cout) {
  __shared__ float tile[32][33];
  int tj = blockIdx.x * 32;  // col base (out row base)
  int ti = blockIdx.y * 32;  // row base
  int t = threadIdx.x;
  int c = t & 31, r0 = t >> 5;
#pragma unroll
  for (int p = 0; p < 4; ++p) {
    int r = r0 + p * 8;
    int gr = ti + r, gc = tj + c;
    tile[r][c] = (gc < C) ? in[(size_t)gr * C + gc] : 0.f;
  }
  __syncthreads();
#pragma unroll
  for (int p = 0; p < 4; ++p) {
    int rr = r0 + p * 8;
    out[(size_t)(tj + rr) * R + (ti + c)] = f2bf(tile[c][rr]);
  }
}

// C[M=8192, NC] = EPI(A[M,K]_f32 @ Bt[NC,K]_bf16^T + bias)
// NC in {256, 64}. A converted fp32->bf16 while staging to LDS.
// TROUT: write transposed bf16 [NC][8192] to Ct instead of f32 C.
template <int NC, int EPI, bool ZDIAG, bool TROUT, bool HASB>
__global__ __launch_bounds__(512)
void gemm_k(const float* __restrict__ A, const u16* __restrict__ Bt,
            const float* __restrict__ bias, float* __restrict__ C,
            u16* __restrict__ Ct, int K, int ncv) {
  __shared__ u16 sA[32 * 64];
  __shared__ u16 sB[NC * 64];
  const int t = threadIdx.x;
  const int lane = t & 63;
  const int w = t >> 6;
  const int rowBase = blockIdx.x * 32;

  constexpr int FR = (NC == 256) ? 2 : 1;
  constexpr int FC = (NC == 256) ? 2 : 1;
  const int rowOff = (NC == 256) ? 0 : ((w >> 2) * 16);
  const int colB = (NC == 256) ? (w * 32) : ((w & 3) * 16);

  f32x4 acc[FR][FC];
#pragma unroll
  for (int a = 0; a < FR; ++a)
#pragma unroll
    for (int b = 0; b < FC; ++b) acc[a][b] = (f32x4){0.f, 0.f, 0.f, 0.f};

  const int ar = t >> 3;  // valid for t<256: 0..31
  const int akc = t & 7;  // k-chunk of 8
  const int br = t >> 1;
  const int bs = t & 1;

  for (int k0 = 0; k0 < K; k0 += 64) {
    if (t < 256) {
      const float* ap = A + (size_t)(rowBase + ar) * K + (k0 + akc * 8);
      float4 f0 = *(const float4*)ap;
      float4 f1 = *(const float4*)(ap + 4);
      float a0 = f0.x, a1 = f0.y, a2 = f0.z, a3 = f0.w;
      float a4 = f1.x, a5 = f1.y, a6 = f1.z, a7 = f1.w;
      if (ZDIAG) {
        int d = (rowBase + ar) - (k0 + akc * 8);
        if (d == 0) a0 = 0.f;
        if (d == 1) a1 = 0.f;
        if (d == 2) a2 = 0.f;
        if (d == 3) a3 = 0.f;
        if (d == 4) a4 = 0.f;
        if (d == 5) a5 = 0.f;
        if (d == 6) a6 = 0.f;
        if (d == 7) a7 = 0.f;
      }
      uint4 q;
      q.x = (unsigned)f2bf(a0) | ((unsigned)f2bf(a1) << 16);
      q.y = (unsigned)f2bf(a2) | ((unsigned)f2bf(a3) << 16);
      q.z = (unsigned)f2bf(a4) | ((unsigned)f2bf(a5) << 16);
      q.w = (unsigned)f2bf(a6) | ((unsigned)f2bf(a7) << 16);
      int off = (ar * 128 + akc * 16) ^ ((ar & 7) << 4);
      *(uint4*)((char*)sA + off) = q;
    }
    if (NC == 256 || t < NC * 2) {
      const uint4* bp = (const uint4*)(Bt + (size_t)br * K + (k0 + bs * 32));
      uint4 q0 = bp[0], q1 = bp[1], q2 = bp[2], q3 = bp[3];
      int ob = br * 128 + bs * 64;
      int sw = (br & 7) << 4;
      *(uint4*)((char*)sB + ((ob) ^ sw)) = q0;
      *(uint4*)((char*)sB + ((ob + 16) ^ sw)) = q1;
      *(uint4*)((char*)sB + ((ob + 32) ^ sw)) = q2;
      *(uint4*)((char*)sB + ((ob + 48) ^ sw)) = q3;
    }
    __syncthreads();
    bf16x8 af[FR][2], bv[FC][2];
#pragma unroll
    for (int fr = 0; fr < FR; ++fr)
#pragma unroll
      for (int ks = 0; ks < 2; ++ks) {
        int rl = rowOff + fr * 16 + (lane & 15);
        int off = (rl * 128 + ks * 64 + (lane >> 4) * 16) ^ ((rl & 7) << 4);
        af[fr][ks] = *(const bf16x8*)((const char*)sA + off);
      }
#pragma unroll
    for (int fc = 0; fc < FC; ++fc)
#pragma unroll
      for (int ks = 0; ks < 2; ++ks) {
        int r = colB + fc * 16 + (lane & 15);
        int off = (r * 128 + ks * 64 + (lane >> 4) * 16) ^ ((r & 7) << 4);
        bv[fc][ks] = *(const bf16x8*)((const char*)sB + off);
      }
#pragma unroll
    for (int fr = 0; fr < FR; ++fr)
#pragma unroll
      for (int fc = 0; fc < FC; ++fc)
#pragma unroll
        for (int ks = 0; ks < 2; ++ks)
          acc[fr][fc] = __builtin_amdgcn_mfma_f32_16x16x32_bf16(
              af[fr][ks], bv[fc][ks], acc[fr][fc], 0, 0, 0);
    __syncthreads();
  }

#pragma unroll
  for (int fr = 0; fr < FR; ++fr)
#pragma unroll
    for (int fc = 0; fc < FC; ++fc) {
      int col = colB + fc * 16 + (lane & 15);
      int rb = rowBase + rowOff + fr * 16 + (lane >> 4) * 4;
      float bvs = 0.f;
      if (HASB) bvs = (col < ncv) ? bias[col] : 0.f;
      float o[4];
#pragma unroll
      for (int j = 0; j < 4; ++j) {
        float xv = acc[fr][fc][j] + bvs;
        if (EPI == 1) xv = fmaxf(xv, 0.f);
        if (EPI == 2) xv = (xv > 0.f) ? xv : 0.2f * xv;
        o[j] = xv;
      }
      if (TROUT) {
        uint2 q;
        q.x = (unsigned)f2bf(o[0]) | ((unsigned)f2bf(o[1]) << 16);
        q.y = (unsigned)f2bf(o[2]) | ((unsigned)f2bf(o[3]) << 16);
        *(uint2*)(Ct + (size_t)col * 8192 + rb) = q;
      } else if (col < ncv) {
        C[(size_t)(rb + 0) * NC + col] = o[0];
        C[(size_t)(rb + 1) * NC + col] = o[1];
        C[(size_t)(rb + 2) * NC + col] = o[2];
        C[(size_t)(rb + 3) * NC + col] = o[3];
      }
    }
}

// learned_prompt = (leaky(G)+1)*base + leaky(B); L2-normalize row; x_in = 0.5*(x+lp/nrm)
__global__ __launch_bounds__(256)
void fuse_k(const float* __restrict__ gl, const float* __restrict__ base,
            const float* __restrict__ bl, const float* __restrict__ x,
            float* __restrict__ xin) {
  int row = blockIdx.x;
  int t = threadIdx.x;
  size_t i = (size_t)row * 256 + t;
  float lp = (gl[i] + 1.f) * base[i] + bl[i];
  float s = lp * lp;
#pragma unroll
  for (int off = 32; off >= 1; off >>= 1) s += __shfl_xor(s, off);
  __shared__ float ws4[4];
  if ((t & 63) == 0) ws4[t >> 6] = s;
  __syncthreads();
  float tot = ws4[0] + ws4[1] + ws4[2] + ws4[3];
  float nrm = fmaxf(sqrtf(tot), 1e-12f);
  xin[i] = 0.5f * (x[i] + lp / nrm);
}

// log_softmax over 40 valid cols of [8192][64] fp32
__global__ __launch_bounds__(256)
void lsm_k(const float* __restrict__ logits, float* __restrict__ out) {
  int t = threadIdx.x;
  int lane = t & 63, w = t >> 6;
  int row = blockIdx.x * 4 + w;
  const float* lr = logits + (size_t)row * 64;
  float v = (lane < 40) ? lr[lane] : -1e30f;
  float m = v;
#pragma unroll
  for (int off = 32; off >= 1; off >>= 1) m = fmaxf(m, __shfl_xor(m, off));
  float e = (lane < 40) ? expf(v - m) : 0.f;
  float s = e;
#pragma unroll
  for (int off = 32; off >= 1; off >>= 1) s += __shfl_xor(s, off);
  float ls = m + logf(s);
  if (lane < 40) out[(size_t)row * 40 + lane] = v - ls;
}

extern "C" void kernel_launch(void* const* d_in, const int* in_sizes, int n_in,
                              void* d_out, int out_size, void* d_ws, size_t ws_size,
                              hipStream_t stream) {
  const float* x = (const float*)d_in[0];
  const float* adj_f = (const float*)d_in[1];
  const float* adj_a = (const float*)d_in[2];
  const float* Wp = (const float*)d_in[3];
  const float* bp = (const float*)d_in[4];
  const float* Wg = (const float*)d_in[5];
  const float* Wb = (const float*)d_in[6];
  const float* W1 = (const float*)d_in[7];
  const float* b1 = (const float*)d_in[8];
  const float* W2 = (const float*)d_in[9];
  const float* b2 = (const float*)d_in[10];
  float* out = (float*)d_out;

  char* ws = (char*)d_ws;
  size_t off = 0;
  auto alloc = [&](size_t bytes) {
    char* p = ws + off;
    off += (bytes + 255) & ~(size_t)255;
    return p;
  };
  u16* xT = (u16*)alloc(256 * 8192 * 2);      // x^T bf16
  u16* featT = (u16*)alloc(256 * 8192 * 2);   // t1^T / t2^T / t3^T bf16
  u16* WpT = (u16*)alloc(256 * 256 * 2);
  u16* WgT = (u16*)alloc(256 * 256 * 2);
  u16* WbT = (u16*)alloc(256 * 256 * 2);
  u16* W1T = (u16*)alloc(256 * 256 * 2);
  u16* W2T = (u16*)alloc(64 * 256 * 2);       // padded to 64 rows
  float* base = (float*)alloc((size_t)8192 * 256 * 4);
  float* neigh = (float*)alloc((size_t)8192 * 256 * 4);
  float* gammaL = (float*)alloc((size_t)8192 * 256 * 4);  // later x_in
  float* betaL = (float*)alloc((size_t)8192 * 256 * 4);   // later h
  float* logits = (float*)alloc((size_t)8192 * 64 * 4);

  dim3 b256(256), b512(512);
  tr_cvt_k<<<dim3(8, 8), b256, 0, stream>>>(Wp, WpT, 256, 256, 256);
  tr_cvt_k<<<dim3(8, 8), b256, 0, stream>>>(Wg, WgT, 256, 256, 256);
  tr_cvt_k<<<dim3(8, 8), b256, 0, stream>>>(Wb, WbT, 256, 256, 256);
  tr_cvt_k<<<dim3(8, 8), b256, 0, stream>>>(W1, W1T, 256, 256, 256);
  tr_cvt_k<<<dim3(2, 8), b256, 0, stream>>>(W2, W2T, 256, 40, 64);
  tr_cvt_k<<<dim3(8, 256), b256, 0, stream>>>(x, xT, 8192, 256, 256);

  // t1^T = (x @ Wp)^T
  gemm_k<256, 0, false, true, false><<<256, b512, 0, stream>>>(x, WpT, nullptr, nullptr, featT, 256, 256);
  // base = relu(adj_f @ t1 + bp)
  gemm_k<256, 1, false, false, true><<<256, b512, 0, stream>>>(adj_f, featT, bp, base, nullptr, 8192, 256);
  // neigh = adj_a(diag=0) @ x
  gemm_k<256, 0, true, false, false><<<256, b512, 0, stream>>>(adj_a, xT, nullptr, neigh, nullptr, 8192, 256);
  // gammaL = leaky(neigh @ Wg)
  gemm_k<256, 2, false, false, false><<<256, b512, 0, stream>>>(neigh, WgT, nullptr, gammaL, nullptr, 256, 256);
  // betaL = leaky(neigh @ Wb)
  gemm_k<256, 2, false, false, false><<<256, b512, 0, stream>>>(neigh, WbT, nullptr, betaL, nullptr, 256, 256);
  // x_in (into gammaL buffer)
  fuse_k<<<8192, b256, 0, stream>>>(gammaL, base, betaL, x, gammaL);
  // t2^T = (x_in @ W1)^T
  gemm_k<256, 0, false, true, false><<<256, b512, 0, stream>>>(gammaL, W1T, nullptr, nullptr, featT, 256, 256);
  // h = relu(adj_a @ t2 + b1)  (into betaL buffer)
  gemm_k<256, 1, false, false, true><<<256, b512, 0, stream>>>(adj_a, featT, b1, betaL, nullptr, 8192, 256);
  // t3^T = (h @ W2)^T  ([64][8192], rows 40..63 zero via W2T padding)
  gemm_k<64, 0, false, true, false><<<256, b512, 0, stream>>>(betaL, W2T, nullptr, nullptr, featT, 256, 64);
  // logits = adj_a @ t3 + b2 (cols < 40)
  gemm_k<64, 0, false, false, true><<<256, b512, 0, stream>>>(adj_a, featT, b2, logits, nullptr, 8192, 40);
  // log_softmax -> out
  lsm_k<<<2048, b256, 0, stream>>>(logits, out);
}

// Round 2
// 459.745 us; speedup vs baseline: 1.6310x; 1.6310x over previous
//
#include <hip/hip_runtime.h>

typedef unsigned short u16;
typedef __attribute__((ext_vector_type(8))) short bf16x8;
typedef __attribute__((ext_vector_type(4))) float f32x4;

__device__ __forceinline__ u16 f2bf(float f) {
  union { float f; unsigned u; } v; v.f = f;
  unsigned r = v.u + 0x7FFFu + ((v.u >> 16) & 1u);
  return (u16)(r >> 16);
}
__device__ __forceinline__ float bf2f(u16 h) {
  union { unsigned u; float f; } v; v.u = ((unsigned)h) << 16; return v.f;
}
__device__ __forceinline__ unsigned pk2(float a, float b) {
  return (unsigned)f2bf(a) | ((unsigned)f2bf(b) << 16);
}
__device__ __forceinline__ void gld16(const void* g, void* l) {
  __builtin_amdgcn_global_load_lds(
      (const __attribute__((address_space(1))) unsigned int*)g,
      (__attribute__((address_space(3))) unsigned int*)l, 16, 0, 0);
}

// transpose + convert: in [R][C] f32 -> out [Cout][R] bf16 (rows c>=C are zero)
__global__ __launch_bounds__(256)
void tr_cvt_k(const float* __restrict__ in, u16* __restrict__ out,
              int R, int C, int Cout) {
  __shared__ float tile[32][33];
  int tj = blockIdx.x * 32, ti = blockIdx.y * 32;
  int t = threadIdx.x, c = t & 31, r0 = t >> 5;
#pragma unroll
  for (int p = 0; p < 4; ++p) {
    int r = r0 + p * 8;
    tile[r][c] = (tj + c < C) ? in[(size_t)(ti + r) * C + (tj + c)] : 0.f;
  }
  __syncthreads();
#pragma unroll
  for (int p = 0; p < 4; ++p) {
    int rr = r0 + p * 8;
    out[(size_t)(tj + rr) * R + (ti + c)] = f2bf(tile[c][rr]);
  }
}

// row-major f32 -> bf16 convert
__global__ __launch_bounds__(256)
void cvt_rm_k(const float* __restrict__ in, u16* __restrict__ out, int n8) {
  int idx = blockIdx.x * 256 + threadIdx.x;
  if (idx >= n8) return;
  float4 f0 = ((const float4*)in)[idx * 2];
  float4 f1 = ((const float4*)in)[idx * 2 + 1];
  uint4 q;
  q.x = pk2(f0.x, f0.y); q.y = pk2(f0.z, f0.w);
  q.z = pk2(f1.x, f1.y); q.w = pk2(f1.z, f1.w);
  ((uint4*)out)[idx] = q;
}

// d[i] = float(bf16(adj[i][i]))
__global__ __launch_bounds__(256)
void diag_k(const float* __restrict__ adj, float* __restrict__ d) {
  int i = blockIdx.x * 256 + threadIdx.x;
  d[i] = bf2f(f2bf(adj[(size_t)i * 8193]));
}

// Big GEMM: part[kp][8192][BN] = A[8192,8192]_f32 @ Bt[BN,8192]^T  (k-panel kp)
// BM=128, BK=64, split-K=4 (panels of 2048), 8 waves, dbuf global_load_lds.
template <int BN>
__global__ __launch_bounds__(512)
void bgemm_k(const float* __restrict__ A, const u16* __restrict__ Bt,
             float* __restrict__ part) {
  __shared__ float sA[2][128 * 64];
  __shared__ u16 sB[2][BN * 64];
  const int t = threadIdx.x, lane = t & 63, w = t >> 6;
  // XCD swizzle: same-kp blocks grouped per XCD
  const int s = ((blockIdx.x & 7) << 5) | (blockIdx.x >> 3);
  const int kp = s >> 6, m = s & 63;
  const size_t mBase = (size_t)m * 128;
  const int k0base = kp * 2048;

  constexpr int FR = (BN == 256) ? 4 : 2;
  constexpr int FC = (BN == 256) ? 4 : 2;
  constexpr int NBIB = BN / 64;  // B stage issues per wave
  const int waveM = (BN == 256) ? ((w >> 2) * 64) : ((w >> 1) * 32);
  const int waveN = (BN == 256) ? ((w & 3) * 64) : ((w & 1) * 32);

  f32x4 acc[FR][FC];
#pragma unroll
  for (int a = 0; a < FR; ++a)
#pragma unroll
    for (int b = 0; b < FC; ++b) acc[a][b] = (f32x4){0.f, 0.f, 0.f, 0.f};

  auto stage = [&](int buf, int tt) {
    const int k0 = k0base + tt * 64;
    // A: 128 rows x 64 f32, 256B/row, swizzle ^((row&7)<<4); 4 issues/wave
#pragma unroll
    for (int i = 0; i < 4; ++i) {
      int lin = ((w * 4 + i) << 10) + (lane << 4);
      int row = lin >> 8;
      int kb = (lin & 255) ^ ((row & 7) << 4);
      const char* g = (const char*)A + (((size_t)(mBase + row)) << 15) +
                      ((size_t)k0 << 2) + kb;
      gld16(g, (char*)sA[buf] + ((w * 4 + i) << 10));
    }
    // B: BN rows x 64 bf16, 128B/row
#pragma unroll
    for (int i = 0; i < NBIB; ++i) {
      int lin = ((w * NBIB + i) << 10) + (lane << 4);
      int n = lin >> 7;
      int kb = (lin & 127) ^ ((n & 7) << 4);
      const char* g = (const char*)Bt + ((size_t)n << 14) + ((size_t)k0 << 1) + kb;
      gld16(g, (char*)sB[buf] + ((w * NBIB + i) << 10));
    }
  };

  stage(0, 0);
  __syncthreads();
  for (int tt = 0; tt < 32; ++tt) {
    const int cur = tt & 1;
    if (tt < 31) stage(cur ^ 1, tt + 1);
    const char* sa = (const char*)sA[cur];
    const char* sb = (const char*)sB[cur];
#pragma unroll
    for (int ks = 0; ks < 2; ++ks) {
      bf16x8 av[FR], bv[FC];
#pragma unroll
      for (int fr = 0; fr < FR; ++fr) {
        int row = waveM + fr * 16 + (lane & 15);
        int base = row * 256 + ks * 128 + ((lane >> 4) * 32);
        int sw = (row & 7) << 4;
        f32x4 x0 = *(const f32x4*)(sa + (base ^ sw));
        f32x4 x1 = *(const f32x4*)(sa + ((base + 16) ^ sw));
        union { bf16x8 v; unsigned u[4]; } pk;
        pk.u[0] = pk2(x0.x, x0.y); pk.u[1] = pk2(x0.z, x0.w);
        pk.u[2] = pk2(x1.x, x1.y); pk.u[3] = pk2(x1.z, x1.w);
        av[fr] = pk.v;
      }
#pragma unroll
      for (int fc = 0; fc < FC; ++fc) {
        int n = waveN + fc * 16 + (lane & 15);
        int off = (n * 128 + ks * 64 + ((lane >> 4) * 16)) ^ ((n & 7) << 4);
        bv[fc] = *(const bf16x8*)(sb + off);
      }
#pragma unroll
      for (int fr = 0; fr < FR; ++fr)
#pragma unroll
        for (int fc = 0; fc < FC; ++fc)
          acc[fr][fc] = __builtin_amdgcn_mfma_f32_16x16x32_bf16(
              av[fr], bv[fc], acc[fr][fc], 0, 0, 0);
    }
    __syncthreads();
  }

  float* pp = part + (size_t)kp * 8192 * BN + mBase * BN;
#pragma unroll
  for (int fr = 0; fr < FR; ++fr)
#pragma unroll
    for (int fc = 0; fc < FC; ++fc) {
      int col = waveN + fc * 16 + (lane & 15);
      int r0 = waveM + fr * 16 + ((lane >> 4) << 2);
#pragma unroll
      for (int j = 0; j < 4; ++j)
        pp[(size_t)(r0 + j) * BN + col] = acc[fr][fc][j];
    }
}

// Small GEMM: M=8192, K=256, A bf16 [8192][256] row-major, Bt [BN][256] bf16.
// Whole B resident in LDS; BM=32; 4 waves. grid (256, nColBlocks)
template <int BN, int EPI, bool TROUT>
__global__ __launch_bounds__(256)
void sgemm_k(const u16* __restrict__ Abf, const u16* __restrict__ Bt,
             float* __restrict__ C, int ldc, u16* __restrict__ Ct) {
  __shared__ u16 sA[32 * 256];
  __shared__ u16 sB[BN * 256];
  const int t = threadIdx.x, lane = t & 63, w = t >> 6;
  const int rowBase = blockIdx.x * 32;
  const u16* bt = Bt + (size_t)blockIdx.y * BN * 256;
  const int colBlk = blockIdx.y * BN;

  // stage A: 16KB, rows 512B; 4 issues/wave
#pragma unroll
  for (int i = 0; i < 4; ++i) {
    int lin = ((w * 4 + i) << 10) + (lane << 4);
    int row = lin >> 9;
    int kb = (lin & 511) ^ ((row & 7) << 4);
    const char* g = (const char*)Abf + ((size_t)(rowBase + row) << 9) + kb;
    gld16(g, (char*)sA + ((w * 4 + i) << 10));
  }
  // stage B: BN*512 bytes; BN/8 issues/wave
#pragma unroll
  for (int i = 0; i < BN / 8; ++i) {
    int lin = ((w * (BN / 8) + i) << 10) + (lane << 4);
    int n = lin >> 9;
    int kb = (lin & 511) ^ ((n & 7) << 4);
    const char* g = (const char*)bt + ((size_t)n << 9) + kb;
    gld16(g, (char*)sB + ((w * (BN / 8) + i) << 10));
  }
  __syncthreads();

  constexpr int FC = BN / 32;
  const int waveM = (w & 1) * 16;
  const int waveN = (w >> 1) * (BN / 2);
  f32x4 acc[FC];
#pragma unroll
  for (int b = 0; b < FC; ++b) acc[b] = (f32x4){0.f, 0.f, 0.f, 0.f};

#pragma unroll
  for (int ks = 0; ks < 8; ++ks) {
    int row = waveM + (lane & 15);
    int offA = (row * 512 + ks * 64 + ((lane >> 4) * 16)) ^ ((row & 7) << 4);
    bf16x8 av = *(const bf16x8*)((const char*)sA + offA);
#pragma unroll
    for (int fc = 0; fc < FC; ++fc) {
      int n = waveN + fc * 16 + (lane & 15);
      int offB = (n * 512 + ks * 64 + ((lane >> 4) * 16)) ^ ((n & 7) << 4);
      bf16x8 bv = *(const bf16x8*)((const char*)sB + offB);
      acc[fc] = __builtin_amdgcn_mfma_f32_16x16x32_bf16(av, bv, acc[fc], 0, 0, 0);
    }
  }

#pragma unroll
  for (int fc = 0; fc < FC; ++fc) {
    int col = waveN + fc * 16 + (lane & 15);
    int r0 = rowBase + waveM + ((lane >> 4) << 2);
    float o[4];
#pragma unroll
    for (int j = 0; j < 4; ++j) {
      float xv = acc[fc][j];
      if (EPI == 1) xv = fmaxf(xv, 0.f);
      if (EPI == 2) xv = (xv > 0.f) ? xv : 0.2f * xv;
      o[j] = xv;
    }
    if (TROUT) {
      uint2 q; q.x = pk2(o[0], o[1]); q.y = pk2(o[2], o[3]);
      *(uint2*)(Ct + (size_t)col * 8192 + r0) = q;
    } else {
      C[(size_t)(r0 + 0) * ldc + colBlk + col] = o[0];
      C[(size_t)(r0 + 1) * ldc + colBlk + col] = o[1];
      C[(size_t)(r0 + 2) * ldc + colBlk + col] = o[2];
      C[(size_t)(r0 + 3) * ldc + colBlk + col] = o[3];
    }
  }
}

// reduce 4 K-panel partials + epilogue. MODE 0: relu(+bias)->f32
// MODE 1: -d[i]*x -> bf16; MODE 2: relu(+bias)->bf16
template <int MODE>
__global__ __launch_bounds__(256)
void reduce_k(const float* __restrict__ part, const float* __restrict__ bias,
              const float* __restrict__ d, const u16* __restrict__ xbf,
              float* __restrict__ Cf, u16* __restrict__ Cb) {
  const int row = blockIdx.x, j = threadIdx.x;
  const size_t i = (size_t)row * 256 + j;
  const size_t S = (size_t)8192 * 256;
  float s = part[i] + part[i + S] + part[i + 2 * S] + part[i + 3 * S];
  if (MODE == 0) { s = fmaxf(s + bias[j], 0.f); Cf[i] = s; }
  if (MODE == 1) { s -= d[row] * bf2f(xbf[i]); Cb[i] = f2bf(s); }
  if (MODE == 2) { s = fmaxf(s + bias[j], 0.f); Cb[i] = f2bf(s); }
}

// reduce logits partials [4][8192][64] + b2, then log_softmax over 40 cols
__global__ __launch_bounds__(256)
void reduce_lsm_k(const float* __restrict__ part, const float* __restrict__ b2,
                  float* __restrict__ out) {
  const int t = threadIdx.x, lane = t & 63, w = t >> 6;
  const int row = blockIdx.x * 4 + w;
  const size_t i = (size_t)row * 64 + lane;
  const size_t S = (size_t)8192 * 64;
  float v = part[i] + part[i + S] + part[i + 2 * S] + part[i + 3 * S];
  v = (lane < 40) ? v + b2[lane] : -1e30f;
  float mx = v;
#pragma unroll
  for (int off = 32; off >= 1; off >>= 1) mx = fmaxf(mx, __shfl_xor(mx, off));
  float e = (lane < 40) ? expf(v - mx) : 0.f;
#pragma unroll
  for (int off = 32; off >= 1; off >>= 1) e += __shfl_xor(e, off);
  float ls = mx + logf(e);
  if (lane < 40) out[(size_t)row * 40 + lane] = v - ls;
}

// lp=(g+1)*base+b; L2-normalize row; xin_bf = bf16(0.5*(x+lp/nrm))
__global__ __launch_bounds__(256)
void fuse_k(const float* __restrict__ gb, const float* __restrict__ base,
            const float* __restrict__ x, u16* __restrict__ xin_bf) {
  const int row = blockIdx.x, t = threadIdx.x;
  const size_t i = (size_t)row * 256 + t;
  float g = gb[(size_t)row * 512 + t];
  float b = gb[(size_t)row * 512 + 256 + t];
  float lp = (g + 1.f) * base[i] + b;
  float s = lp * lp;
#pragma unroll
  for (int off = 32; off >= 1; off >>= 1) s += __shfl_xor(s, off);
  __shared__ float ws4[4];
  if ((t & 63) == 0) ws4[t >> 6] = s;
  __syncthreads();
  float nrm = fmaxf(sqrtf(ws4[0] + ws4[1] + ws4[2] + ws4[3]), 1e-12f);
  xin_bf[i] = f2bf(0.5f * (x[i] + lp / nrm));
}

extern "C" void kernel_launch(void* const* d_in, const int* in_sizes, int n_in,
                              void* d_out, int out_size, void* d_ws, size_t ws_size,
                              hipStream_t stream) {
  const float* x = (const float*)d_in[0];
  const float* adj_f = (const float*)d_in[1];
  const float* adj_a = (const float*)d_in[2];
  const float* Wp = (const float*)d_in[3];
  const float* bp = (const float*)d_in[4];
  const float* Wg = (const float*)d_in[5];
  const float* Wb = (const float*)d_in[6];
  const float* W1 = (const float*)d_in[7];
  const float* b1 = (const float*)d_in[8];
  const float* W2 = (const float*)d_in[9];
  const float* b2 = (const float*)d_in[10];
  float* out = (float*)d_out;

  char* ws = (char*)d_ws;
  size_t off = 0;
  auto alloc = [&](size_t bytes) {
    char* p = ws + off;
    off += (bytes + 255) & ~(size_t)255;
    return p;
  };
  float* part = (float*)alloc((size_t)4 * 8192 * 256 * 4);  // 32 MB
  u16* featT = (u16*)alloc((size_t)256 * 8192 * 2);
  u16* featT64 = (u16*)alloc((size_t)64 * 8192 * 2);
  u16* xT = (u16*)alloc((size_t)256 * 8192 * 2);
  u16* xbf = (u16*)alloc((size_t)8192 * 256 * 2);
  u16* xin_bf = (u16*)alloc((size_t)8192 * 256 * 2);
  u16* neigh_bf = (u16*)alloc((size_t)8192 * 256 * 2);
  u16* h_bf = (u16*)alloc((size_t)8192 * 256 * 2);
  float* base = (float*)alloc((size_t)8192 * 256 * 4);
  float* gbuf = (float*)alloc((size_t)8192 * 512 * 4);
  u16* WpT = (u16*)alloc(256 * 256 * 2);
  u16* WgbT = (u16*)alloc(512 * 256 * 2);
  u16* W1T = (u16*)alloc(256 * 256 * 2);
  u16* W2T = (u16*)alloc(64 * 256 * 2);
  float* dd = (float*)alloc(8192 * 4);

  dim3 b256(256), b512(512);
  tr_cvt_k<<<dim3(8, 8), b256, 0, stream>>>(Wp, WpT, 256, 256, 256);
  tr_cvt_k<<<dim3(8, 8), b256, 0, stream>>>(Wg, WgbT, 256, 256, 256);
  tr_cvt_k<<<dim3(8, 8), b256, 0, stream>>>(Wb, WgbT + 256 * 256, 256, 256, 256);
  tr_cvt_k<<<dim3(8, 8), b256, 0, stream>>>(W1, W1T, 256, 256, 256);
  tr_cvt_k<<<dim3(2, 8), b256, 0, stream>>>(W2, W2T, 256, 40, 64);
  tr_cvt_k<<<dim3(8, 256), b256, 0, stream>>>(x, xT, 8192, 256, 256);
  cvt_rm_k<<<1024, b256, 0, stream>>>(x, xbf, 8192 * 256 / 8);
  diag_k<<<32, b256, 0, stream>>>(adj_a, dd);

  // neighbor = adj_a @ x (diag removed in reduce)
  bgemm_k<256><<<256, b512, 0, stream>>>(adj_a, xT, part);
  reduce_k<1><<<8192, b256, 0, stream>>>(part, nullptr, dd, xbf, nullptr, neigh_bf);
  // gamma|beta = leaky(neigh @ [Wg|Wb])
  sgemm_k<256, 2, false><<<dim3(256, 2), b256, 0, stream>>>(neigh_bf, WgbT, gbuf, 512, nullptr);
  // t1^T = (x @ Wp)^T
  sgemm_k<256, 0, true><<<dim3(256, 1), b256, 0, stream>>>(xbf, WpT, nullptr, 0, featT);
  // base = relu(adj_f @ t1 + bp)
  bgemm_k<256><<<256, b512, 0, stream>>>(adj_f, featT, part);
  reduce_k<0><<<8192, b256, 0, stream>>>(part, bp, nullptr, nullptr, base, nullptr);
  // x_in
  fuse_k<<<8192, b256, 0, stream>>>(gbuf, base, x, xin_bf);
  // t2^T
  sgemm_k<256, 0, true><<<dim3(256, 1), b256, 0, stream>>>(xin_bf, W1T, nullptr, 0, featT);
  // h = relu(adj_a @ t2 + b1)
  bgemm_k<256><<<256, b512, 0, stream>>>(adj_a, featT, part);
  reduce_k<2><<<8192, b256, 0, stream>>>(part, b1, nullptr, nullptr, nullptr, h_bf);
  // t3^T
  sgemm_k<64, 0, true><<<dim3(256, 1), b256, 0, stream>>>(h_bf, W2T, nullptr, 0, featT64);
  // logits partials + fused log_softmax
  bgemm_k<64><<<256, b512, 0, stream>>>(adj_a, featT64, part);
  reduce_lsm_k<<<2048, b256, 0, stream>>>(part, b2, out);
}